// Round 8
// baseline (167.817 us; speedup 1.0000x reference)
//
#include <hip/hip_runtime.h>

#define B_ 16
#define P_ 65536
#define T_ 64
#define APT 4                 // anchors per thread
#define BLK 256
#define APB (APT * BLK)       // anchors per block = 1024
#define NBLK (P_ / APB)       // 64 blocks per image
#define NPART (B_ * NBLK)     // 1024 partial slots == k2 block size
#define WCH (APB / 4)         // anchors per wave in phase 2 = 256

__device__ __forceinline__ float rcpf(float x) { return __builtin_amdgcn_rcpf(x); }

// inter/union of one (anchor, truth) pair. Non-contractible ops; operand order
// identical everywhere so k1 phase1/phase2 and k2 reproduce bit-identical values.
__device__ __forceinline__ void iou_iu(const float4& a, float aa, const float4& tb,
                                       float at, float& inter, float& u) {
    float lx = fmaxf(tb.x, a.x), ly = fmaxf(tb.y, a.y);
    float rx = fminf(tb.z, a.z), ry = fminf(tb.w, a.w);
    float w = fmaxf(__fsub_rn(rx, lx), 0.0f);
    float h = fmaxf(__fsub_rn(ry, ly), 0.0f);
    inter = __fmul_rn(w, h);
    u     = __fsub_rn(__fadd_rn(at, aa), inter);
}

// iou1 > iou2 without division: i1/u1 > i2/u2  <=>  i1*u2 > i2*u1 (u > 0)
__device__ __forceinline__ bool gt_iou(float i1, float u1, float i2, float u2) {
    return __fmul_rn(i1, u2) > __fmul_rn(i2, u1);
}

__device__ __forceinline__ float sl1(float d) {
    float ad = fabsf(d);
    return (ad < 1.0f) ? 0.5f * ad * ad : ad - 0.5f;
}

// smooth-L1 of loc vs SSD-encoded (truth m, anchor a)
__device__ __forceinline__ float sl1_enc(const float4& l, const float4& a, const float4& m) {
    float aw = a.z - a.x, ah = a.w - a.y;
    float acx = (a.x + a.z) * 0.5f, acy = (a.y + a.w) * 0.5f;
    float mcx = (m.x + m.z) * 0.5f, mcy = (m.y + m.w) * 0.5f;
    float mw = m.z - m.x, mh = m.w - m.y;
    float g0 = (mcx - acx) / (0.1f * aw);
    float g1 = (mcy - acy) / (0.1f * ah);
    float g2 = __logf(mw / aw) * 5.0f;   // /0.2
    float g3 = __logf(mh / ah) * 5.0f;
    return sl1(l.x - g0) + sl1(l.y - g1) + sl1(l.z - g2) + sl1(l.w - g3);
}

// ---------------------------------------------------------------------------
// k1, two phases:
//  Phase 1 (per-anchor): lane owns APT anchors, loops truths; per-anchor
//    argmax only (no cross-lane work) -> labels, CE, smooth-L1.
//  Phase 2 (per-truth, transposed): lane = truth; wave scans its 256-anchor
//    chunk from LDS (wave-uniform broadcast reads); lane-local running argmax;
//    one u64 key per (wave,truth), 4-way combine -> best_blk.
// ---------------------------------------------------------------------------
__global__ __launch_bounds__(256) void k1(const float4* __restrict__ loc,
                                          const float2* __restrict__ conf,
                                          const float4* __restrict__ anchors,
                                          const float4* __restrict__ targets,
                                          unsigned long long* __restrict__ best_blk,
                                          float4* __restrict__ part) {
    const int b    = blockIdx.y;
    const int bx   = blockIdx.x;
    const int tid  = threadIdx.x;
    const int base = bx * APB;

    __shared__ float4 sa[APB];                  // block anchors (16 KB)
    __shared__ float  saa[APB];                 // block anchor areas (4 KB)
    __shared__ float4 tt[T_];
    __shared__ float  ta[T_];
    __shared__ unsigned long long arr[4][T_];   // per-wave, per-truth keys

    if (tid < T_) {
        float4 t = targets[b * T_ + tid];
        tt[tid] = t;
        ta[tid] = (t.z - t.x) * (t.w - t.y);
    }

    float4 a[APT]; float aa[APT];
#pragma unroll
    for (int i = 0; i < APT; ++i) {
        a[i]  = anchors[(size_t)b * P_ + (base + i * BLK + tid)];   // coalesced
        aa[i] = (a[i].z - a[i].x) * (a[i].w - a[i].y);
        sa[i * BLK + tid]  = a[i];
        saa[i * BLK + tid] = aa[i];
    }
    __syncthreads();

    // ---- Phase 1: per-anchor best truth (registers only, no cross-lane) ----
    float ib[APT], ub[APT]; int bt[APT];
#pragma unroll
    for (int i = 0; i < APT; ++i) { ib[i] = 0.0f; ub[i] = 1.0f; bt[i] = 0; }

    for (int t = 0; t < T_; ++t) {
        const float4 tb = tt[t];
        const float  at = ta[t];
#pragma unroll
        for (int i = 0; i < APT; ++i) {
            float inter, u;
            iou_iu(a[i], aa[i], tb, at, inter, u);
            // ascending t + strict > == jnp.argmax first-occurrence over truths
            if (gt_iou(inter, u, ib[i], ub[i])) { ib[i] = inter; ub[i] = u; bt[i] = t; }
        }
    }

    // ---- Phase 2: per-truth argmax, lane = truth, wave-local anchor chunk ----
    {
        const int w    = tid >> 6;
        const int lane = tid & 63;
        const float4 mytb = tt[lane];
        const float  myat = ta[lane];
        float li = 0.0f, lu = 1.0f; unsigned lp = 0u;
#pragma unroll 4
        for (int j = w * WCH; j < w * WCH + WCH; ++j) {
            float4 aj = sa[j];                  // wave-uniform addr -> broadcast
            float aaj = saa[j];
            float inter, u;
            iou_iu(aj, aaj, mytb, myat, inter, u);
            // ascending p + strict > == smaller p on ties
            if (gt_iou(inter, u, li, lu)) { li = inter; lu = u; lp = (unsigned)(base + j); }
        }
        float iou = __fmul_rn(li, rcpf(lu));
        arr[w][lane] = ((unsigned long long)__float_as_uint(iou) << 32) |
                       (unsigned long long)(0xFFFFFFFFu - lp);
    }
    __syncthreads();

    if (tid < T_) {                              // block combine, coalesced store
        unsigned long long k = arr[0][tid];
        k = (arr[1][tid] > k) ? arr[1][tid] : k;
        k = (arr[2][tid] > k) ? arr[2][tid] : k;
        k = (arr[3][tid] > k) ? arr[3][tid] : k;
        best_blk[(size_t)(b * NBLK + bx) * T_ + tid] = k;
    }

    // ---- Epilogue: per-anchor losses (k2 applies force-match deltas) ----
    float ll = 0.0f, cn = 0.0f, ces = 0.0f;
#pragma unroll
    for (int i = 0; i < APT; ++i) {
        // exact threshold: ib/ub >= 0.5  <=>  2*ib >= ub
        int lab = (__fmul_rn(2.0f, ib[i]) >= ub[i]);
        float2 c = conf[(size_t)b * P_ + (base + i * BLK + tid)];
        float mx  = fmaxf(c.x, c.y);
        float lse = mx + __logf(__expf(c.x - mx) + __expf(c.y - mx));
        ces += lse - (lab ? c.y : c.x);
        if (lab) {
            float4 l = loc[(size_t)b * P_ + (base + i * BLK + tid)];
            ll += sl1_enc(l, a[i], tt[bt[i]]);
            cn += 1.0f;
        }
    }
#pragma unroll
    for (int off = 32; off; off >>= 1) {
        ll  += __shfl_down(ll,  off, 64);
        cn  += __shfl_down(cn,  off, 64);
        ces += __shfl_down(ces, off, 64);
    }
    __shared__ float r[3][4];
    const int lane = tid & 63, w = tid >> 6;
    if (lane == 0) { r[0][w] = ll; r[1][w] = cn; r[2][w] = ces; }
    __syncthreads();
    if (tid == 0) {
        part[b * NBLK + bx] = make_float4(r[0][0] + r[0][1] + r[0][2] + r[0][3],
                                          r[1][0] + r[1][1] + r[1][2] + r[1][3],
                                          r[2][0] + r[2][1] + r[2][2] + r[2][3], 0.0f);
    }
}

// ---------------------------------------------------------------------------
// k2: single block, 1024 threads = (b, t) pairs. Reduces block keys and loss
// partials, applies force-match fixup deltas, writes the final scalar.
// (~2-5 us; the measured ~85 us residual is fixed harness overhead.)
// ---------------------------------------------------------------------------
__global__ __launch_bounds__(1024) void k2(const float4* __restrict__ loc,
                                           const float2* __restrict__ conf,
                                           const float4* __restrict__ anchors,
                                           const float4* __restrict__ targets,
                                           const unsigned long long* __restrict__ best_blk,
                                           const float4* __restrict__ part,
                                           float* __restrict__ out) {
    const int tid = threadIdx.x;
    const int b = tid >> 6, t = tid & 63;

    __shared__ float4   tt[B_][T_];
    __shared__ float    ta[B_][T_];
    __shared__ unsigned bp[B_][T_];
    __shared__ float    red[3][16];
    __shared__ float    dacc[3];
    if (tid < 3) dacc[tid] = 0.0f;

    float4 tb0 = targets[tid];
    tt[b][t] = tb0;
    ta[b][t] = (tb0.z - tb0.x) * (tb0.w - tb0.y);

    // final per-truth argmax over the 64 block keys (coalesced u64 loads)
    unsigned long long k = 0ull;
    for (int blk = 0; blk < NBLK; ++blk) {
        unsigned long long o = best_blk[(size_t)(b * NBLK + blk) * T_ + t];
        k = (o > k) ? o : k;
    }
    bp[b][t] = 0xFFFFFFFFu - (unsigned)(k & 0xFFFFFFFFull);

    // reduce the 1024 per-block loss partials (one float4 per thread)
    float4 pr = part[tid];
    float ll = pr.x, cn = pr.y, ces = pr.z;
#pragma unroll
    for (int off = 32; off; off >>= 1) {
        ll  += __shfl_down(ll,  off, 64);
        cn  += __shfl_down(cn,  off, 64);
        ces += __shfl_down(ces, off, 64);
    }
    if ((tid & 63) == 0) { red[0][tid >> 6] = ll; red[1][tid >> 6] = cn; red[2][tid >> 6] = ces; }
    __syncthreads();

    // force-match fixup: sequential scatter semantics -> last truth wins
    float dll = 0.0f, dcn = 0.0f, dce = 0.0f;
    const unsigned mine = bp[b][t];
    bool dup = false;
    for (int t2 = t + 1; t2 < T_; ++t2) dup |= (bp[b][t2] == mine);
    if (!dup) {
        const int pidx = (int)mine;
        const float4 a  = anchors[(size_t)b * P_ + pidx];
        const float  aa = (a.z - a.x) * (a.w - a.y);
        float ibv = 0.0f, ubv = 1.0f; int btv = 0;
        for (int t2 = 0; t2 < T_; ++t2) {        // bit-identical to k1 phase 1
            float inter, u;
            iou_iu(a, aa, tt[b][t2], ta[b][t2], inter, u);
            if (gt_iou(inter, u, ibv, ubv)) { ibv = inter; ubv = u; btv = t2; }
        }
        int lab_old = (__fmul_rn(2.0f, ibv) >= ubv);
        float2 c = conf[(size_t)b * P_ + pidx];
        dce = (lab_old ? c.y : c.x) - c.y;       // new label is always 1
        float4 l = loc[(size_t)b * P_ + pidx];
        dll = sl1_enc(l, a, tt[b][t]);
        if (lab_old) dll -= sl1_enc(l, a, tt[b][btv]);
        dcn = lab_old ? 0.0f : 1.0f;
    }
#pragma unroll
    for (int off = 32; off; off >>= 1) {
        dll += __shfl_down(dll, off, 64);
        dcn += __shfl_down(dcn, off, 64);
        dce += __shfl_down(dce, off, 64);
    }
    if ((tid & 63) == 0) {
        atomicAdd(&dacc[0], dll);
        atomicAdd(&dacc[1], dcn);
        atomicAdd(&dacc[2], dce);
    }
    __syncthreads();

    if (tid == 0) {
        double L = 0.0, C = 0.0, E = 0.0;
        for (int w = 0; w < 16; ++w) { L += red[0][w]; C += red[1][w]; E += red[2][w]; }
        L += dacc[0]; C += dacc[1]; E += dacc[2];
        out[0] = (float)(L / C + E / ((double)P_ * (double)(B_ * P_)));
    }
}

extern "C" void kernel_launch(void* const* d_in, const int* in_sizes, int n_in,
                              void* d_out, int out_size, void* d_ws, size_t ws_size,
                              hipStream_t stream) {
    const float4* loc     = (const float4*)d_in[0];
    const float2* conf    = (const float2*)d_in[1];
    const float4* anchors = (const float4*)d_in[2];
    const float4* targets = (const float4*)d_in[3];

    // ws layout (no zeroing needed; k1 writes every slot before k2 reads):
    //   [0, 512K)    best_blk: u64[B*NBLK*T]
    //   [512K, 528K) part:     float4[NPART]
    unsigned long long* best_blk = (unsigned long long*)d_ws;
    float4* part = (float4*)((char*)d_ws + (size_t)B_ * NBLK * T_ * sizeof(unsigned long long));

    dim3 g1(NBLK, B_);
    k1<<<g1, dim3(BLK), 0, stream>>>(loc, conf, anchors, targets, best_blk, part);

    k2<<<dim3(1), dim3(1024), 0, stream>>>(loc, conf, anchors, targets, best_blk, part,
                                           (float*)d_out);
}

// Round 9
// 162.071 us; speedup vs baseline: 1.0355x; 1.0355x over previous
//
#include <hip/hip_runtime.h>

#define B_ 16
#define P_ 65536
#define T_ 64
#define APT 4                 // anchors per thread
#define BLK 256
#define APB (APT * BLK)       // anchors per block = 1024
#define NBLK (P_ / APB)       // 64 blocks per image
#define NPART (B_ * NBLK)     // 1024 partial slots == k2 block size

__device__ __forceinline__ float rcpf(float x) { return __builtin_amdgcn_rcpf(x); }

// ---- DPP 64-lane reduces (pure VALU, zero LDS traffic) --------------------
template <int CTRL>
__device__ __forceinline__ float dppf(float v) {
    // old = v: out-of-range source lanes keep current value (identity for max)
    return __int_as_float(__builtin_amdgcn_update_dpp(
        __float_as_int(v), __float_as_int(v), CTRL, 0xf, 0xf, false));
}
template <int CTRL>
__device__ __forceinline__ unsigned dppu(unsigned v) {
    return (unsigned)__builtin_amdgcn_update_dpp((int)v, (int)v, CTRL, 0xf, 0xf, false);
}
// After these, lane 63 holds the reduction over all 64 lanes.
__device__ __forceinline__ float wave_max_f32(float v) {
    v = fmaxf(v, dppf<0x111>(v));   // row_shr:1
    v = fmaxf(v, dppf<0x112>(v));   // row_shr:2
    v = fmaxf(v, dppf<0x114>(v));   // row_shr:4
    v = fmaxf(v, dppf<0x118>(v));   // row_shr:8
    v = fmaxf(v, dppf<0x142>(v));   // row_bcast:15
    v = fmaxf(v, dppf<0x143>(v));   // row_bcast:31
    return v;
}
__device__ __forceinline__ unsigned wave_min_u32(unsigned v) {
    unsigned o;
    o = dppu<0x111>(v); v = (o < v) ? o : v;
    o = dppu<0x112>(v); v = (o < v) ? o : v;
    o = dppu<0x114>(v); v = (o < v) ? o : v;
    o = dppu<0x118>(v); v = (o < v) ? o : v;
    o = dppu<0x142>(v); v = (o < v) ? o : v;
    o = dppu<0x143>(v); v = (o < v) ? o : v;
    return v;
}

// (inter, c=area_t+area_a) of one (anchor, truth) pair. Non-contractible ops;
// identical helper in k1 and k2 so discrete decisions agree bit-for-bit.
// NOTE: union is never needed for comparisons:
//   iou1 > iou2  <=>  I1/(c1-I1) > I2/(c2-I2)  <=>  I1*c2 > I2*c1
__device__ __forceinline__ void iou_ic(const float4& a, float aa, const float4& tb,
                                       float at, float& I, float& c) {
    float lx = fmaxf(tb.x, a.x), ly = fmaxf(tb.y, a.y);
    float rx = fminf(tb.z, a.z), ry = fminf(tb.w, a.w);
    float w = fmaxf(__fsub_rn(rx, lx), 0.0f);
    float h = fmaxf(__fsub_rn(ry, ly), 0.0f);
    I = __fmul_rn(w, h);
    c = __fadd_rn(at, aa);
}
__device__ __forceinline__ bool gt2(float I1, float c1, float I2, float c2) {
    return __fmul_rn(I1, c2) > __fmul_rn(I2, c1);
}

__device__ __forceinline__ float sl1(float d) {
    float ad = fabsf(d);
    return (ad < 1.0f) ? 0.5f * ad * ad : ad - 0.5f;
}

// smooth-L1 of loc vs SSD-encoded (truth m, anchor a)
__device__ __forceinline__ float sl1_enc(const float4& l, const float4& a, const float4& m) {
    float aw = a.z - a.x, ah = a.w - a.y;
    float acx = (a.x + a.z) * 0.5f, acy = (a.y + a.w) * 0.5f;
    float mcx = (m.x + m.z) * 0.5f, mcy = (m.y + m.w) * 0.5f;
    float mw = m.z - m.x, mh = m.w - m.y;
    float g0 = (mcx - acx) / (0.1f * aw);
    float g1 = (mcy - acy) / (0.1f * ah);
    float g2 = __logf(mw / aw) * 5.0f;   // /0.2
    float g3 = __logf(mh / ah) * 5.0f;
    return sl1(l.x - g0) + sl1(l.y - g1) + sl1(l.z - g2) + sl1(l.w - g3);
}

// ---------------------------------------------------------------------------
// k1: SINGLE pass over the T x P IoU matrix (each pair evaluated once).
//  - per anchor: running argmax over truths via exact cross-mult (labels/encode)
//  - per truth: lane-local candidate (exact cross-mult), then f32 DPP max of
//    rcp'd iou + readlane + exact min-p tie-break via u32 DPP min
//  - per block: u64 keys -> best_blk; (loss_l, cnt, ce) partials -> part
// ---------------------------------------------------------------------------
__global__ __launch_bounds__(256) void k1(const float4* __restrict__ loc,
                                          const float2* __restrict__ conf,
                                          const float4* __restrict__ anchors,
                                          const float4* __restrict__ targets,
                                          unsigned long long* __restrict__ best_blk,
                                          float4* __restrict__ part) {
    const int b    = blockIdx.y;
    const int bx   = blockIdx.x;
    const int tid  = threadIdx.x;
    const int base = bx * APB;
    const int lane = tid & 63;
    const int w    = tid >> 6;

    __shared__ float4 tt[T_];
    __shared__ float  ta[T_];
    __shared__ unsigned long long arr[4][T_];   // per-wave, per-truth keys

    if (tid < T_) {
        float4 t = targets[b * T_ + tid];
        tt[tid] = t;
        ta[tid] = (t.z - t.x) * (t.w - t.y);
    }
    __syncthreads();

    float4 a[APT]; float aa[APT]; int p[APT];
#pragma unroll
    for (int i = 0; i < APT; ++i) {
        p[i]  = base + i * BLK + tid;            // coalesced
        a[i]  = anchors[(size_t)b * P_ + p[i]];
        aa[i] = (a[i].z - a[i].x) * (a[i].w - a[i].y);
    }

    // per-anchor running best over truths as (I, c) pair; cb=1 dummy (I*1>0*c <=> I>0)
    float ib[APT], cb[APT]; int bt[APT];
#pragma unroll
    for (int i = 0; i < APT; ++i) { ib[i] = 0.0f; cb[i] = 1.0f; bt[i] = 0; }

#pragma unroll 2
    for (int t = 0; t < T_; ++t) {
        const float4 tb = tt[t];
        const float  at = ta[t];
        float li = 0.0f, lc = 1.0f; unsigned lp = 0u;   // lane best for truth t
#pragma unroll
        for (int i = 0; i < APT; ++i) {
            float I, c;
            iou_ic(a[i], aa[i], tb, at, I, c);
            // ascending t + strict > == jnp.argmax first-occurrence over truths
            if (gt2(I, c, ib[i], cb[i])) { ib[i] = I; cb[i] = c; bt[i] = t; }
            // ascending p within thread + strict > == smaller p on ties
            if (gt2(I, c, li, lc)) { li = I; lc = c; lp = (unsigned)p[i]; }
        }
        // lane's iou (rcp approx, only for cross-lane ordering / final key)
        float iou  = __fmul_rn(li, rcpf(__fsub_rn(lc, li)));
        float m    = wave_max_f32(iou);
        float smax = __int_as_float(__builtin_amdgcn_readlane(__float_as_int(m), 63));
        // exact smallest-p among lanes whose iou equals the max
        unsigned cand = (iou == smax) ? lp : 0xFFFFFFFFu;
        cand = wave_min_u32(cand);
        if (lane == 63)
            arr[w][t] = ((unsigned long long)__float_as_uint(smax) << 32) |
                        (unsigned long long)(0xFFFFFFFFu - cand);
    }
    __syncthreads();

    if (tid < T_) {                              // block combine, coalesced store
        unsigned long long k = arr[0][tid];
        k = (arr[1][tid] > k) ? arr[1][tid] : k;
        k = (arr[2][tid] > k) ? arr[2][tid] : k;
        k = (arr[3][tid] > k) ? arr[3][tid] : k;
        best_blk[(size_t)(b * NBLK + bx) * T_ + tid] = k;
    }

    // ---- per-anchor losses (pre-force-match; k2 applies deltas) ----
    float ll = 0.0f, cn = 0.0f, ces = 0.0f;
#pragma unroll
    for (int i = 0; i < APT; ++i) {
        // iou >= 0.5  <=>  I/(c-I) >= 0.5  <=>  3I >= c   (exact-real equivalent)
        int lab = (__fmul_rn(3.0f, ib[i]) >= cb[i]);
        float2 c = conf[(size_t)b * P_ + p[i]];
        float mx  = fmaxf(c.x, c.y);
        float lse = mx + __logf(__expf(c.x - mx) + __expf(c.y - mx));
        ces += lse - (lab ? c.y : c.x);
        if (lab) {
            float4 l = loc[(size_t)b * P_ + p[i]];
            ll += sl1_enc(l, a[i], tt[bt[i]]);
            cn += 1.0f;
        }
    }
#pragma unroll
    for (int off = 32; off; off >>= 1) {
        ll  += __shfl_down(ll,  off, 64);
        cn  += __shfl_down(cn,  off, 64);
        ces += __shfl_down(ces, off, 64);
    }
    __shared__ float r[3][4];
    if (lane == 0) { r[0][w] = ll; r[1][w] = cn; r[2][w] = ces; }
    __syncthreads();
    if (tid == 0) {
        part[b * NBLK + bx] = make_float4(r[0][0] + r[0][1] + r[0][2] + r[0][3],
                                          r[1][0] + r[1][1] + r[1][2] + r[1][3],
                                          r[2][0] + r[2][1] + r[2][2] + r[2][3], 0.0f);
    }
}

// ---------------------------------------------------------------------------
// k2: single block, 1024 threads = (b, t) pairs. Reduces block keys and loss
// partials, applies force-match fixup deltas, writes the final scalar.
// (~2-5 us; the measured ~85 us residual is fixed harness overhead.)
// ---------------------------------------------------------------------------
__global__ __launch_bounds__(1024) void k2(const float4* __restrict__ loc,
                                           const float2* __restrict__ conf,
                                           const float4* __restrict__ anchors,
                                           const float4* __restrict__ targets,
                                           const unsigned long long* __restrict__ best_blk,
                                           const float4* __restrict__ part,
                                           float* __restrict__ out) {
    const int tid = threadIdx.x;
    const int b = tid >> 6, t = tid & 63;

    __shared__ float4   tt[B_][T_];
    __shared__ float    ta[B_][T_];
    __shared__ unsigned bp[B_][T_];
    __shared__ float    red[3][16];
    __shared__ float    dacc[3];
    if (tid < 3) dacc[tid] = 0.0f;

    float4 tb0 = targets[tid];
    tt[b][t] = tb0;
    ta[b][t] = (tb0.z - tb0.x) * (tb0.w - tb0.y);

    // final per-truth argmax over the 64 block keys (coalesced u64 loads)
    unsigned long long k = 0ull;
    for (int blk = 0; blk < NBLK; ++blk) {
        unsigned long long o = best_blk[(size_t)(b * NBLK + blk) * T_ + t];
        k = (o > k) ? o : k;
    }
    bp[b][t] = 0xFFFFFFFFu - (unsigned)(k & 0xFFFFFFFFull);

    // reduce the 1024 per-block loss partials (one float4 per thread)
    float4 pr = part[tid];
    float ll = pr.x, cn = pr.y, ces = pr.z;
#pragma unroll
    for (int off = 32; off; off >>= 1) {
        ll  += __shfl_down(ll,  off, 64);
        cn  += __shfl_down(cn,  off, 64);
        ces += __shfl_down(ces, off, 64);
    }
    if ((tid & 63) == 0) { red[0][tid >> 6] = ll; red[1][tid >> 6] = cn; red[2][tid >> 6] = ces; }
    __syncthreads();

    // force-match fixup: sequential scatter semantics -> last truth wins
    float dll = 0.0f, dcn = 0.0f, dce = 0.0f;
    const unsigned mine = bp[b][t];
    bool dup = false;
    for (int t2 = t + 1; t2 < T_; ++t2) dup |= (bp[b][t2] == mine);
    if (!dup) {
        const int pidx = (int)mine;
        const float4 a  = anchors[(size_t)b * P_ + pidx];
        const float  aa = (a.z - a.x) * (a.w - a.y);
        float ibv = 0.0f, cbv = 1.0f; int btv = 0;
        for (int t2 = 0; t2 < T_; ++t2) {        // bit-identical to k1's decisions
            float I, c;
            iou_ic(a, aa, tt[b][t2], ta[b][t2], I, c);
            if (gt2(I, c, ibv, cbv)) { ibv = I; cbv = c; btv = t2; }
        }
        int lab_old = (__fmul_rn(3.0f, ibv) >= cbv);
        float2 c = conf[(size_t)b * P_ + pidx];
        dce = (lab_old ? c.y : c.x) - c.y;       // new label is always 1
        float4 l = loc[(size_t)b * P_ + pidx];
        dll = sl1_enc(l, a, tt[b][t]);
        if (lab_old) dll -= sl1_enc(l, a, tt[b][btv]);
        dcn = lab_old ? 0.0f : 1.0f;
    }
#pragma unroll
    for (int off = 32; off; off >>= 1) {
        dll += __shfl_down(dll, off, 64);
        dcn += __shfl_down(dcn, off, 64);
        dce += __shfl_down(dce, off, 64);
    }
    if ((tid & 63) == 0) {
        atomicAdd(&dacc[0], dll);
        atomicAdd(&dacc[1], dcn);
        atomicAdd(&dacc[2], dce);
    }
    __syncthreads();

    if (tid == 0) {
        double L = 0.0, C = 0.0, E = 0.0;
        for (int w = 0; w < 16; ++w) { L += red[0][w]; C += red[1][w]; E += red[2][w]; }
        L += dacc[0]; C += dacc[1]; E += dacc[2];
        out[0] = (float)(L / C + E / ((double)P_ * (double)(B_ * P_)));
    }
}

extern "C" void kernel_launch(void* const* d_in, const int* in_sizes, int n_in,
                              void* d_out, int out_size, void* d_ws, size_t ws_size,
                              hipStream_t stream) {
    const float4* loc     = (const float4*)d_in[0];
    const float2* conf    = (const float2*)d_in[1];
    const float4* anchors = (const float4*)d_in[2];
    const float4* targets = (const float4*)d_in[3];

    // ws layout (no zeroing needed; k1 writes every slot before k2 reads):
    //   [0, 512K)    best_blk: u64[B*NBLK*T]
    //   [512K, 528K) part:     float4[NPART]
    unsigned long long* best_blk = (unsigned long long*)d_ws;
    float4* part = (float4*)((char*)d_ws + (size_t)B_ * NBLK * T_ * sizeof(unsigned long long));

    dim3 g1(NBLK, B_);
    k1<<<g1, dim3(BLK), 0, stream>>>(loc, conf, anchors, targets, best_blk, part);

    k2<<<dim3(1), dim3(1024), 0, stream>>>(loc, conf, anchors, targets, best_blk, part,
                                           (float*)d_out);
}

// Round 10
// 160.792 us; speedup vs baseline: 1.0437x; 1.0080x over previous
//
#include <hip/hip_runtime.h>

#define B_ 16
#define P_ 65536
#define T_ 64
#define APT 4                 // anchors per thread
#define BLK 256
#define APB (APT * BLK)       // anchors per block = 1024
#define NBLK (P_ / APB)       // 64 blocks per image
#define NPART (B_ * NBLK)     // 1024 partial slots == k2 block size

__device__ __forceinline__ float rcpf(float x) { return __builtin_amdgcn_rcpf(x); }

// ---- DPP 64-lane reduces (pure VALU, zero LDS traffic) --------------------
template <int CTRL>
__device__ __forceinline__ float dppf(float v) {
    // old = v: out-of-range source lanes keep current value (identity for max)
    return __int_as_float(__builtin_amdgcn_update_dpp(
        __float_as_int(v), __float_as_int(v), CTRL, 0xf, 0xf, false));
}
template <int CTRL>
__device__ __forceinline__ unsigned dppu(unsigned v) {
    return (unsigned)__builtin_amdgcn_update_dpp((int)v, (int)v, CTRL, 0xf, 0xf, false);
}
// After these, lane 63 holds the reduction over all 64 lanes.
__device__ __forceinline__ float wave_max_f32(float v) {
    v = fmaxf(v, dppf<0x111>(v));   // row_shr:1
    v = fmaxf(v, dppf<0x112>(v));   // row_shr:2
    v = fmaxf(v, dppf<0x114>(v));   // row_shr:4
    v = fmaxf(v, dppf<0x118>(v));   // row_shr:8
    v = fmaxf(v, dppf<0x142>(v));   // row_bcast:15
    v = fmaxf(v, dppf<0x143>(v));   // row_bcast:31
    return v;
}
__device__ __forceinline__ unsigned wave_min_u32(unsigned v) {
    unsigned o;
    o = dppu<0x111>(v); v = (o < v) ? o : v;
    o = dppu<0x112>(v); v = (o < v) ? o : v;
    o = dppu<0x114>(v); v = (o < v) ? o : v;
    o = dppu<0x118>(v); v = (o < v) ? o : v;
    o = dppu<0x142>(v); v = (o < v) ? o : v;
    o = dppu<0x143>(v); v = (o < v) ? o : v;
    return v;
}

// r = iou via one rcp. Non-contractible ops; the IDENTICAL helper is used in
// k1's pair loop and k2's fixup so all discrete decisions agree bit-for-bit.
// union = at + aa - I > 0 always (positive box areas), so r is finite, in [0,1].
__device__ __forceinline__ float iou_r(const float4& a, float aa, const float4& tb,
                                       float at) {
    float lx = fmaxf(tb.x, a.x), ly = fmaxf(tb.y, a.y);
    float rx = fminf(tb.z, a.z), ry = fminf(tb.w, a.w);
    float w = fmaxf(__fsub_rn(rx, lx), 0.0f);
    float h = fmaxf(__fsub_rn(ry, ly), 0.0f);
    float I = __fmul_rn(w, h);
    float u = __fsub_rn(__fadd_rn(at, aa), I);
    return __fmul_rn(I, rcpf(u));
}

__device__ __forceinline__ float sl1(float d) {
    float ad = fabsf(d);
    return (ad < 1.0f) ? 0.5f * ad * ad : ad - 0.5f;
}

// smooth-L1 of loc vs SSD-encoded (truth m, anchor a)
__device__ __forceinline__ float sl1_enc(const float4& l, const float4& a, const float4& m) {
    float aw = a.z - a.x, ah = a.w - a.y;
    float acx = (a.x + a.z) * 0.5f, acy = (a.y + a.w) * 0.5f;
    float mcx = (m.x + m.z) * 0.5f, mcy = (m.y + m.w) * 0.5f;
    float mw = m.z - m.x, mh = m.w - m.y;
    float g0 = (mcx - acx) / (0.1f * aw);
    float g1 = (mcy - acy) / (0.1f * ah);
    float g2 = __logf(mw / aw) * 5.0f;   // /0.2
    float g3 = __logf(mh / ah) * 5.0f;
    return sl1(l.x - g0) + sl1(l.y - g1) + sl1(l.z - g2) + sl1(l.w - g3);
}

// ---------------------------------------------------------------------------
// k1: SINGLE pass over the T x P IoU matrix (each pair evaluated once).
//  - per pair: one scalar r = iou (rcp); both argmax directions update on r
//  - per anchor: running (br, bt) -> labels, CE, smooth-L1
//  - per truth: lane-local (lr, lp), f32 DPP max + exact min-p tie-break
//  - per block: u64 keys -> best_blk; (loss_l, cnt, ce) partials -> part
// ---------------------------------------------------------------------------
__global__ __launch_bounds__(256) void k1(const float4* __restrict__ loc,
                                          const float2* __restrict__ conf,
                                          const float4* __restrict__ anchors,
                                          const float4* __restrict__ targets,
                                          unsigned long long* __restrict__ best_blk,
                                          float4* __restrict__ part) {
    const int b    = blockIdx.y;
    const int bx   = blockIdx.x;
    const int tid  = threadIdx.x;
    const int base = bx * APB;
    const int lane = tid & 63;
    const int w    = tid >> 6;

    __shared__ float4 tt[T_];
    __shared__ float  ta[T_];
    __shared__ unsigned long long arr[4][T_];   // per-wave, per-truth keys

    if (tid < T_) {
        float4 t = targets[b * T_ + tid];
        tt[tid] = t;
        ta[tid] = (t.z - t.x) * (t.w - t.y);
    }
    __syncthreads();

    float4 a[APT]; float aa[APT]; int p[APT];
#pragma unroll
    for (int i = 0; i < APT; ++i) {
        p[i]  = base + i * BLK + tid;            // coalesced
        a[i]  = anchors[(size_t)b * P_ + p[i]];
        aa[i] = (a[i].z - a[i].x) * (a[i].w - a[i].y);
    }

    // per-anchor running best over truths (init -1 so r=0 at t=0 wins -> bt=0,
    // matching jnp.argmax first-occurrence on all-zero columns)
    float br[APT]; int bt[APT];
#pragma unroll
    for (int i = 0; i < APT; ++i) { br[i] = -1.0f; bt[i] = 0; }

#pragma unroll 2
    for (int t = 0; t < T_; ++t) {
        const float4 tb = tt[t];
        const float  at = ta[t];
        float lr = -1.0f; unsigned lp = 0u;      // lane best for truth t
#pragma unroll
        for (int i = 0; i < APT; ++i) {
            float r = iou_r(a[i], aa[i], tb, at);
            // ascending t + strict > == first-occurrence over truths
            if (r > br[i]) { br[i] = r; bt[i] = t; }
            // ascending p within thread + strict > == smaller p on ties
            if (r > lr)    { lr = r; lp = (unsigned)p[i]; }
        }
        float m    = wave_max_f32(lr);
        float smax = __int_as_float(__builtin_amdgcn_readlane(__float_as_int(m), 63));
        // exact smallest-p among lanes whose r equals the wave max
        unsigned cand = (lr == smax) ? lp : 0xFFFFFFFFu;
        cand = wave_min_u32(cand);
        if (lane == 63)
            arr[w][t] = ((unsigned long long)__float_as_uint(smax) << 32) |
                        (unsigned long long)(0xFFFFFFFFu - cand);
    }
    __syncthreads();

    if (tid < T_) {                              // block combine, coalesced store
        unsigned long long k = arr[0][tid];
        k = (arr[1][tid] > k) ? arr[1][tid] : k;
        k = (arr[2][tid] > k) ? arr[2][tid] : k;
        k = (arr[3][tid] > k) ? arr[3][tid] : k;
        best_blk[(size_t)(b * NBLK + bx) * T_ + tid] = k;
    }

    // ---- per-anchor losses (pre-force-match; k2 applies deltas) ----
    float ll = 0.0f, cn = 0.0f, ces = 0.0f;
#pragma unroll
    for (int i = 0; i < APT; ++i) {
        int lab = (br[i] >= 0.5f);
        float2 c = conf[(size_t)b * P_ + p[i]];
        float mx  = fmaxf(c.x, c.y);
        float lse = mx + __logf(__expf(c.x - mx) + __expf(c.y - mx));
        ces += lse - (lab ? c.y : c.x);
        if (lab) {
            float4 l = loc[(size_t)b * P_ + p[i]];
            ll += sl1_enc(l, a[i], tt[bt[i]]);
            cn += 1.0f;
        }
    }
#pragma unroll
    for (int off = 32; off; off >>= 1) {
        ll  += __shfl_down(ll,  off, 64);
        cn  += __shfl_down(cn,  off, 64);
        ces += __shfl_down(ces, off, 64);
    }
    __shared__ float r[3][4];
    if (lane == 0) { r[0][w] = ll; r[1][w] = cn; r[2][w] = ces; }
    __syncthreads();
    if (tid == 0) {
        part[b * NBLK + bx] = make_float4(r[0][0] + r[0][1] + r[0][2] + r[0][3],
                                          r[1][0] + r[1][1] + r[1][2] + r[1][3],
                                          r[2][0] + r[2][1] + r[2][2] + r[2][3], 0.0f);
    }
}

// ---------------------------------------------------------------------------
// k2: single block, 1024 threads = (b, t) pairs. Reduces block keys and loss
// partials, applies force-match fixup deltas, writes the final scalar.
// (~2-5 us; the measured ~85 us residual is harness restore/poison dispatches.)
// ---------------------------------------------------------------------------
__global__ __launch_bounds__(1024) void k2(const float4* __restrict__ loc,
                                           const float2* __restrict__ conf,
                                           const float4* __restrict__ anchors,
                                           const float4* __restrict__ targets,
                                           const unsigned long long* __restrict__ best_blk,
                                           const float4* __restrict__ part,
                                           float* __restrict__ out) {
    const int tid = threadIdx.x;
    const int b = tid >> 6, t = tid & 63;

    __shared__ float4   tt[B_][T_];
    __shared__ float    ta[B_][T_];
    __shared__ unsigned bp[B_][T_];
    __shared__ float    red[3][16];
    __shared__ float    dacc[3];
    if (tid < 3) dacc[tid] = 0.0f;

    float4 tb0 = targets[tid];
    tt[b][t] = tb0;
    ta[b][t] = (tb0.z - tb0.x) * (tb0.w - tb0.y);

    // final per-truth argmax over the 64 block keys (coalesced u64 loads)
    unsigned long long k = 0ull;
    for (int blk = 0; blk < NBLK; ++blk) {
        unsigned long long o = best_blk[(size_t)(b * NBLK + blk) * T_ + t];
        k = (o > k) ? o : k;
    }
    bp[b][t] = 0xFFFFFFFFu - (unsigned)(k & 0xFFFFFFFFull);

    // reduce the 1024 per-block loss partials (one float4 per thread)
    float4 pr = part[tid];
    float ll = pr.x, cn = pr.y, ces = pr.z;
#pragma unroll
    for (int off = 32; off; off >>= 1) {
        ll  += __shfl_down(ll,  off, 64);
        cn  += __shfl_down(cn,  off, 64);
        ces += __shfl_down(ces, off, 64);
    }
    if ((tid & 63) == 0) { red[0][tid >> 6] = ll; red[1][tid >> 6] = cn; red[2][tid >> 6] = ces; }
    __syncthreads();

    // force-match fixup: sequential scatter semantics -> last truth wins
    float dll = 0.0f, dcn = 0.0f, dce = 0.0f;
    const unsigned mine = bp[b][t];
    bool dup = false;
    for (int t2 = t + 1; t2 < T_; ++t2) dup |= (bp[b][t2] == mine);
    if (!dup) {
        const int pidx = (int)mine;
        const float4 a  = anchors[(size_t)b * P_ + pidx];
        const float  aa = (a.z - a.x) * (a.w - a.y);
        float brv = -1.0f; int btv = 0;
        for (int t2 = 0; t2 < T_; ++t2) {        // bit-identical to k1's decisions
            float r = iou_r(a, aa, tt[b][t2], ta[b][t2]);
            if (r > brv) { brv = r; btv = t2; }
        }
        int lab_old = (brv >= 0.5f);
        float2 c = conf[(size_t)b * P_ + pidx];
        dce = (lab_old ? c.y : c.x) - c.y;       // new label is always 1
        float4 l = loc[(size_t)b * P_ + pidx];
        dll = sl1_enc(l, a, tt[b][t]);
        if (lab_old) dll -= sl1_enc(l, a, tt[b][btv]);
        dcn = lab_old ? 0.0f : 1.0f;
    }
#pragma unroll
    for (int off = 32; off; off >>= 1) {
        dll += __shfl_down(dll, off, 64);
        dcn += __shfl_down(dcn, off, 64);
        dce += __shfl_down(dce, off, 64);
    }
    if ((tid & 63) == 0) {
        atomicAdd(&dacc[0], dll);
        atomicAdd(&dacc[1], dcn);
        atomicAdd(&dacc[2], dce);
    }
    __syncthreads();

    if (tid == 0) {
        double L = 0.0, C = 0.0, E = 0.0;
        for (int w = 0; w < 16; ++w) { L += red[0][w]; C += red[1][w]; E += red[2][w]; }
        L += dacc[0]; C += dacc[1]; E += dacc[2];
        out[0] = (float)(L / C + E / ((double)P_ * (double)(B_ * P_)));
    }
}

extern "C" void kernel_launch(void* const* d_in, const int* in_sizes, int n_in,
                              void* d_out, int out_size, void* d_ws, size_t ws_size,
                              hipStream_t stream) {
    const float4* loc     = (const float4*)d_in[0];
    const float2* conf    = (const float2*)d_in[1];
    const float4* anchors = (const float4*)d_in[2];
    const float4* targets = (const float4*)d_in[3];

    // ws layout (no zeroing needed; k1 writes every slot before k2 reads):
    //   [0, 512K)    best_blk: u64[B*NBLK*T]
    //   [512K, 528K) part:     float4[NPART]
    unsigned long long* best_blk = (unsigned long long*)d_ws;
    float4* part = (float4*)((char*)d_ws + (size_t)B_ * NBLK * T_ * sizeof(unsigned long long));

    dim3 g1(NBLK, B_);
    k1<<<g1, dim3(BLK), 0, stream>>>(loc, conf, anchors, targets, best_blk, part);

    k2<<<dim3(1), dim3(1024), 0, stream>>>(loc, conf, anchors, targets, best_blk, part,
                                           (float*)d_out);
}